// Round 6
// baseline (1006.752 us; speedup 1.0000x reference)
//
#include <hip/hip_runtime.h>

#define TT  128
#define CC  256
#define VV  25
#define KK  3
#define GG  9
#define LL  9
#define NCC 60
#define CINN 3
#define TV    (TT*VV)          // 3200 (input x layout)
#define N4    4096             // Tt rows: n = t*32+v
#define KDIM2 (CC*GG)          // 2304
#define UR    ((TT+8)*32)      // 4352 Ut2 rows: row = (t+8)*32+v
#define YSTR  104              // LDS Yt row stride (shorts)
#define HSTR  264              // LDS sH row stride (shorts), bank-skewed
#define GRID  256

typedef __attribute__((ext_vector_type(8))) short bf16x8;
typedef __attribute__((ext_vector_type(4))) float f32x4;
typedef unsigned short us16;
typedef unsigned long long ull;

__device__ __forceinline__ us16 f2bf(float f) {
    union { float f; unsigned u; } a; a.f = f;
    unsigned r = a.u + 0x7fff + ((a.u >> 16) & 1);
    return (us16)(r >> 16);
}
__device__ __forceinline__ float bf2f(us16 u) {
    union { unsigned u; float f; } a; a.u = ((unsigned)u) << 16; return a.f;
}
__device__ __forceinline__ bf16x8 ld8(const us16* p) { return *(const bf16x8*)p; }

// ---- agent-coherent (memory-side, sc0 sc1) accessors for inter-XCD buffers ----

__device__ __forceinline__ unsigned ald4(const void* p) {
    return __hip_atomic_load((const unsigned*)p, __ATOMIC_RELAXED, __HIP_MEMORY_SCOPE_AGENT);
}
__device__ __forceinline__ void ast4(void* p, unsigned v) {
    __hip_atomic_store((unsigned*)p, v, __ATOMIC_RELAXED, __HIP_MEMORY_SCOPE_AGENT);
}
__device__ __forceinline__ ull ald8(const void* p) {
    return __hip_atomic_load((const ull*)p, __ATOMIC_RELAXED, __HIP_MEMORY_SCOPE_AGENT);
}
__device__ __forceinline__ void ast8(void* p, ull v) {
    __hip_atomic_store((ull*)p, v, __ATOMIC_RELAXED, __HIP_MEMORY_SCOPE_AGENT);
}
__device__ __forceinline__ bf16x8 ald16v(const us16* p) {
    union { ull q[2]; bf16x8 v; } u;
    u.q[0] = ald8(p); u.q[1] = ald8(p + 4);
    return u.v;
}

// ---------------- device-scope grid barrier (layer-end only) ----------------

__device__ __forceinline__ void gbar(unsigned* bar) {
    asm volatile("s_waitcnt vmcnt(0)" ::: "memory");  // write-through stores visible
    __syncthreads();
    if (threadIdx.x == 0) {
        unsigned g = __hip_atomic_load(bar + 1, __ATOMIC_RELAXED, __HIP_MEMORY_SCOPE_AGENT);
        unsigned a = __hip_atomic_fetch_add(bar, 1u, __ATOMIC_RELAXED, __HIP_MEMORY_SCOPE_AGENT);
        if (a == GRID - 1) {
            __hip_atomic_store(bar, 0u, __ATOMIC_RELAXED, __HIP_MEMORY_SCOPE_AGENT);
            __hip_atomic_store(bar + 1, g + 1u, __ATOMIC_RELAXED, __HIP_MEMORY_SCOPE_AGENT);
        } else {
            while (__hip_atomic_load(bar + 1, __ATOMIC_RELAXED, __HIP_MEMORY_SCOPE_AGENT) == g)
                __builtin_amdgcn_s_sleep(2);
        }
    }
    __syncthreads();
}

// ---------------- merged prep kernel ----------------

#define PN1 (LL*KK*CC*CC)
#define PN2 (LL*CC*CC*GG)
#define PN3 (LL*KK*32*32)
#define PN4 (LL*CC*32)
#define PTOT (PN1+PN2+PN3+PN4)

__global__ void k_prep(const float* __restrict__ Wg, const float* __restrict__ Wt,
                       const float* __restrict__ A, const float* __restrict__ imp,
                       const float* __restrict__ bg,
                       us16* __restrict__ Wgb, us16* __restrict__ Wt2b,
                       us16* __restrict__ AlTb, float* __restrict__ bgAl,
                       unsigned* __restrict__ bar) {
    int i = blockIdx.x * 256 + threadIdx.x;
    if (i < 144) bar[i] = 0u;                  // bar[0..7] + uflag[136]
    if (i < PN1) {
        Wgb[i] = f2bf(Wg[i]);
    } else if (i < PN1 + PN2) {
        int j = i - PN1;
        int kk = j % (CC*GG);
        int o  = (j / (CC*GG)) % CC;
        int l  = j / (CC*CC*GG);
        int g = kk >> 8, c = kk & 255;
        Wt2b[j] = f2bf(Wt[((size_t)(l*CC + o)*CC + c)*GG + g]);
    } else if (i < PN1 + PN2 + PN3) {
        int j = i - PN1 - PN2;
        int v = j & 31, w = (j >> 5) & 31;
        int lk = j >> 10, k = lk % KK, l = lk / KK;
        float val = 0.f;
        if (v < VV && w < VV)
            val = A[(k*VV+v)*VV + w] * imp[((size_t)(l*KK+k)*VV+v)*VV + w];
        AlTb[j] = f2bf(val);
    } else if (i < PTOT) {
        int j = i - PN1 - PN2 - PN3;
        int w = j & 31, c = (j >> 5) & 255, l = j >> 13;
        float s = 0.f;
        if (w < VV) {
            for (int k = 0; k < KK; k++) {
                float col = 0.f;
                for (int v = 0; v < VV; v++)
                    col += A[(k*VV+v)*VV + w] * imp[((size_t)(l*KK+k)*VV+v)*VV + w];
                s += bg[l*KK*CC + k*CC + c] * col;
            }
        }
        bgAl[j] = s;
    }
}

// ---------------- block reduce (sum, sumsq) ----------------

__device__ __forceinline__ void blk_reduce2(float& s, float& q, float* red) {
    #pragma unroll
    for (int off = 32; off; off >>= 1) {
        s += __shfl_down(s, off);
        q += __shfl_down(q, off);
    }
    int lane = threadIdx.x & 63, w = threadIdx.x >> 6;
    if (lane == 0) { red[w] = s; red[4+w] = q; }
    __syncthreads();
    s = red[0]+red[1]+red[2]+red[3];
    q = red[4]+red[5]+red[6]+red[7];
}

// ---------------- fused persistent kernel (dataflow gcn->gemm2) ----------------
// Per layer: gcn blocks flag their Ut2 row-block when done (vmcnt-drained,
// per-frame uflag = l+1); gemm2 tile (mt,nt) spins only on its 10 row-blocks
// [2nt, 2nt+9] and starts while other frames' gcn still runs. The wait set
// also covers the Tt WAR (readers gcn(l,2nt),(l,2nt+1) flag r=2nt+8,2nt+9).
// One gbar per layer (after gemm2) handles Ut2/H overwrite hazards.

struct FA {
    const float *x, *lniw, *lnib, *Win, *bin;
    const float *bt, *ln2w, *ln2b;
    const float *ln1w, *ln1b;
    const us16  *Wgb, *AlTb, *Wt2b;
    const float *bgAl;
    const float *Wout, *bout;
    us16 *HTb0, *HTb1, *Tt, *Ut2;
    unsigned *bar;
    float *out;
};

__global__ __launch_bounds__(256, 1) void k_fused(FA a) {
    const int bid = blockIdx.x, tid = threadIdx.x;
    __shared__ __align__(16) us16 Yt[CC*YSTR];     // 53.2 KB
    __shared__ __align__(16) us16 sH[32*HSTR];     // 16.9 KB
    __shared__ float red[8];
    __shared__ float sx[80];
    __shared__ float sh[80];
    const int wave = tid >> 6, lane = tid & 63, quad = lane >> 4, l16 = lane & 15;
    const int t = bid;

    us16* hPrev = a.HTb0;
    us16* hNext = a.HTb1;
    unsigned* Ut32 = (unsigned*)a.Ut2;
    const unsigned* Tt32 = (const unsigned*)a.Tt;
    unsigned* uflag = a.bar + 8;

    #pragma unroll 1
    for (int l = 0; l < LL; l++) {
        const us16*  WgbL  = a.Wgb  + (size_t)l*KK*CC*CC;
        const us16*  AlTbL = a.AlTb + (size_t)l*KK*32*32;
        const float* bgAlL = a.bgAl + (size_t)l*CC*32;
        const float* lnwL  = a.ln1w + (size_t)l*CC*VV;
        const float* lnbL  = a.ln1b + (size_t)l*CC*VV;
        us16* Hout = (l == 0) ? hPrev : hNext;

        if (t >= TT && t < TT + 8) {               // pad frames: relu(ln1_b)
            int tp = t - TT, c = tid;
            #pragma unroll
            for (int w = 0; w < 32; w++) {
                float u = (w < VV) ? fmaxf(lnbL[c*VV + w], 0.f) : 0.f;
                sH[w*256 + c] = f2bf(u);           // stage [w][c] in LDS
            }
            __syncthreads();
            for (int j = tid; j < 32*128; j += 256) {
                int w = j >> 7, u = j & 127;
                unsigned lo = sH[w*256 + 2*u], hi = sH[w*256 + 2*u + 1];
                ast4(Ut32 + ((size_t)(tp*32 + w))*128 + u, lo | (hi << 16));
            }
            asm volatile("s_waitcnt vmcnt(0)" ::: "memory");
            __syncthreads();
            if (tid == 0) ast4(&uflag[tp], (unsigned)(l + 1));
        } else if (t < TT) {
            if (l == 0) {
                // ---- h^0 = W_in @ LN_in(x_t) + b_in ----
                if (tid < CINN*VV)
                    sx[tid] = a.x[(size_t)(tid/VV)*TV + t*VV + (tid%VV)];
                __syncthreads();
                float s = 0.f, q = 0.f;
                for (int i = 0; i < CINN*VV; i++) { float v = sx[i]; s += v; q += v*v; }
                float m  = s * (1.f/75.f);
                float var = q * (1.f/75.f) - m*m;
                float rs = rsqrtf(var + 1e-5f);
                if (tid < CINN*VV)
                    sh[tid] = (sx[tid]-m)*rs*a.lniw[tid] + a.lnib[tid];
                __syncthreads();
                int c = tid;
                float w0 = a.Win[c*3+0], w1 = a.Win[c*3+1], w2 = a.Win[c*3+2], bb = a.bin[c];
                #pragma unroll
                for (int v = 0; v < VV; v++) {
                    float acc = bb + w0*sh[v] + w1*sh[VV+v] + w2*sh[2*VV+v];
                    sH[v*HSTR + c] = f2bf(acc);
                }
                #pragma unroll
                for (int v = VV; v < 32; v++)
                    sH[v*HSTR + c] = 0;
                __syncthreads();
            } else {
                // ---- h^l = relu(LN2(Tt + bt) + resid), staged sc1 reads ----
                unsigned* stgT = (unsigned*)Yt;            // 12.8 KB
                unsigned* stgR = stgT + 3200;              // 12.8 KB
                const unsigned* Hp32 = (const unsigned*)hPrev;
                for (int j = tid; j < 3200; j += 256) {
                    int v = j >> 7, u = j & 127;
                    stgT[j] = ald4(Tt32 + ((size_t)t*32 + v)*128 + u);
                }
                if (t >= 4)
                    for (int j = tid; j < 3200; j += 256) {
                        int v = j >> 7, u = j & 127;
                        stgR[j] = ald4(Hp32 + ((size_t)(t-4)*32 + v)*128 + u);
                    }
                __syncthreads();
                const float* btv = a.bt   + (size_t)(l-1)*CC;
                const float* l2w = a.ln2w + (size_t)(l-1)*CC*VV;
                const float* l2b = a.ln2b + (size_t)(l-1)*CC*VV;
                int c = tid;
                float btc = btv[c];
                float vals[VV];
                float s = 0.f, q = 0.f;
                #pragma unroll
                for (int v = 0; v < VV; v++) {
                    float xv = bf2f(((const us16*)stgT)[v*256 + c]) + btc;
                    vals[v] = xv; s += xv; q += xv*xv;
                }
                blk_reduce2(s, q, red);
                float m = s * (1.f/6400.f);
                float var = q * (1.f/6400.f) - m*m;
                float rs = rsqrtf(var + 1e-5f);
                #pragma unroll
                for (int v = 0; v < VV; v++) {
                    float res = (t >= 4) ? bf2f(((const us16*)stgR)[v*256 + c]) : 0.f;
                    float o = fmaxf((vals[v]-m)*rs*l2w[c*VV+v] + l2b[c*VV+v] + res, 0.f);
                    sH[v*HSTR + c] = f2bf(o);
                }
                #pragma unroll
                for (int v = VV; v < 32; v++)
                    sH[v*HSTR + c] = 0;
                __syncthreads();
            }

            // ---- staged write-through of h to HTb (rows v<VV only) ----
            {
                unsigned* H32o = (unsigned*)Hout;
                for (int j = tid; j < 3200; j += 256) {
                    int v = j >> 7, u = j & 127;
                    unsigned lo = sH[v*HSTR + 2*u], hi = sH[v*HSTR + 2*u + 1];
                    ast4(H32o + ((size_t)t*32 + v)*128 + u, lo | (hi << 16));
                }
            }
            __syncthreads();

            // ---- phase 2 operand prefetch (lands during phase 1) ----
            bf16x8 al[2][3];
            #pragma unroll
            for (int nt = 0; nt < 2; nt++)
                #pragma unroll
                for (int s = 0; s < 3; s++)
                    al[nt][s] = ld8(AlTbL + (size_t)(s*32 + nt*16 + l16)*32 + quad*8);

            // ---- phase 1: Y = Wg @ h  (M=768, N=32, K=256) ----
            bf16x8 bf[2][8];
            #pragma unroll
            for (int nt = 0; nt < 2; nt++)
                #pragma unroll
                for (int s = 0; s < 8; s++)
                    bf[nt][s] = *(const bf16x8*)(sH + (nt*16 + l16)*HSTR + s*32 + quad*8);

            bf16x8 wA0,wA1,wA2,wA3,wA4,wA5,wA6,wA7;
            bf16x8 wB0,wB1,wB2,wB3,wB4,wB5,wB6,wB7;
            bf16x8 wC0,wC1,wC2,wC3,wC4,wC5,wC6,wC7;

#define PLD(S, mtv) { \
    const us16* ap_ = WgbL + (size_t)(wave*192 + (mtv)*16 + l16)*CC + quad*8; \
    S##0 = ld8(ap_);       S##1 = ld8(ap_ + 32); \
    S##2 = ld8(ap_ + 64);  S##3 = ld8(ap_ + 96); \
    S##4 = ld8(ap_ + 128); S##5 = ld8(ap_ + 160); \
    S##6 = ld8(ap_ + 192); S##7 = ld8(ap_ + 224); }
#define PMFW(S, mtv) { \
    f32x4 p0a = {}, p0b = {}, p1a = {}, p1b = {}; \
    p0a = __builtin_amdgcn_mfma_f32_16x16x32_bf16(S##0, bf[0][0], p0a,0,0,0); \
    p1a = __builtin_amdgcn_mfma_f32_16x16x32_bf16(S##0, bf[1][0], p1a,0,0,0); \
    p0b = __builtin_amdgcn_mfma_f32_16x16x32_bf16(S##1, bf[0][1], p0b,0,0,0); \
    p1b = __builtin_amdgcn_mfma_f32_16x16x32_bf16(S##1, bf[1][1], p1b,0,0,0); \
    p0a = __builtin_amdgcn_mfma_f32_16x16x32_bf16(S##2, bf[0][2], p0a,0,0,0); \
    p1a = __builtin_amdgcn_mfma_f32_16x16x32_bf16(S##2, bf[1][2], p1a,0,0,0); \
    p0b = __builtin_amdgcn_mfma_f32_16x16x32_bf16(S##3, bf[0][3], p0b,0,0,0); \
    p1b = __builtin_amdgcn_mfma_f32_16x16x32_bf16(S##3, bf[1][3], p1b,0,0,0); \
    p0a = __builtin_amdgcn_mfma_f32_16x16x32_bf16(S##4, bf[0][4], p0a,0,0,0); \
    p1a = __builtin_amdgcn_mfma_f32_16x16x32_bf16(S##4, bf[1][4], p1a,0,0,0); \
    p0b = __builtin_amdgcn_mfma_f32_16x16x32_bf16(S##5, bf[0][5], p0b,0,0,0); \
    p1b = __builtin_amdgcn_mfma_f32_16x16x32_bf16(S##5, bf[1][5], p1b,0,0,0); \
    p0a = __builtin_amdgcn_mfma_f32_16x16x32_bf16(S##6, bf[0][6], p0a,0,0,0); \
    p1a = __builtin_amdgcn_mfma_f32_16x16x32_bf16(S##6, bf[1][6], p1a,0,0,0); \
    p0b = __builtin_amdgcn_mfma_f32_16x16x32_bf16(S##7, bf[0][7], p0b,0,0,0); \
    p1b = __builtin_amdgcn_mfma_f32_16x16x32_bf16(S##7, bf[1][7], p1b,0,0,0); \
    int mb_ = wave*192 + (mtv)*16 + quad*4; \
    _Pragma("unroll") \
    for (int r_ = 0; r_ < 4; r_++) { \
        int m_ = mb_ + r_; \
        int base_ = (m_ & 255)*YSTR + (m_ >> 8)*32 + l16; \
        Yt[base_]      = f2bf(p0a[r_] + p0b[r_]); \
        Yt[base_ + 16] = f2bf(p1a[r_] + p1b[r_]); \
    } }

            PLD(wA, 0); PLD(wB, 1); PLD(wC, 2);
            #pragma unroll 1
            for (int mt = 0; mt < 9; mt += 3) {
                PMFW(wA, mt);     PLD(wA, mt + 3);
                PMFW(wB, mt + 1); PLD(wB, mt + 4);
                PMFW(wC, mt + 2); PLD(wC, mt + 5);
            }
            PMFW(wA, 9); PMFW(wB, 10); PMFW(wC, 11);
#undef PLD
#undef PMFW
            __syncthreads();

            // ---- phase 2: Z[c][w] = sum_{k,v} Yt[c][k*32+v] * Al[k][v][w] ----
            f32x4 z[4][2];
            #pragma unroll
            for (int mt = 0; mt < 4; mt++) { z[mt][0] = (f32x4){}; z[mt][1] = (f32x4){}; }
            #pragma unroll
            for (int mt = 0; mt < 4; mt++)
                #pragma unroll
                for (int s = 0; s < 3; s++) {
                    bf16x8 av = *(const bf16x8*)(Yt + (wave*64 + mt*16 + l16)*YSTR + s*32 + quad*8);
                    z[mt][0] = __builtin_amdgcn_mfma_f32_16x16x32_bf16(av, al[0][s], z[mt][0], 0,0,0);
                    z[mt][1] = __builtin_amdgcn_mfma_f32_16x16x32_bf16(av, al[1][s], z[mt][1], 0,0,0);
                }

            // ---- bias fold + LN1 + ReLU -> Ut2 (write-through) ----
            float s_ = 0.f, q_ = 0.f;
            #pragma unroll
            for (int mt = 0; mt < 4; mt++)
                #pragma unroll
                for (int nt = 0; nt < 2; nt++)
                    #pragma unroll
                    for (int r = 0; r < 4; r++) {
                        int c = wave*64 + mt*16 + quad*4 + r;
                        int w = nt*16 + l16;
                        float zb = z[mt][nt][r] + bgAlL[c*32 + w];
                        z[mt][nt][r] = zb;
                        if (w < VV) { s_ += zb; q_ += zb*zb; }
                    }
            blk_reduce2(s_, q_, red);
            float m = s_ * (1.f/6400.f);
            float var = q_ * (1.f/6400.f) - m*m;
            float rs = rsqrtf(var + 1e-5f);
            #pragma unroll
            for (int mt = 0; mt < 4; mt++)
                #pragma unroll
                for (int nt = 0; nt < 2; nt++) {
                    int w = nt*16 + l16;
                    if (w < VV) {
                        int c0 = wave*64 + mt*16 + quad*4;
                        ushort4 pk;
                        float u0 = fmaxf((z[mt][nt][0]-m)*rs*lnwL[(c0+0)*VV+w] + lnbL[(c0+0)*VV+w], 0.f);
                        float u1 = fmaxf((z[mt][nt][1]-m)*rs*lnwL[(c0+1)*VV+w] + lnbL[(c0+1)*VV+w], 0.f);
                        float u2 = fmaxf((z[mt][nt][2]-m)*rs*lnwL[(c0+2)*VV+w] + lnbL[(c0+2)*VV+w], 0.f);
                        float u3 = fmaxf((z[mt][nt][3]-m)*rs*lnwL[(c0+3)*VV+w] + lnbL[(c0+3)*VV+w], 0.f);
                        pk.x = f2bf(u0); pk.y = f2bf(u1); pk.z = f2bf(u2); pk.w = f2bf(u3);
                        union { ull q; ushort4 s4; } pu; pu.s4 = pk;
                        ast8(a.Ut2 + (size_t)((t+8)*32 + w)*CC + c0, pu.q);
                    }
                }
            for (int j = tid; j < 7*128; j += 256) {
                int r = VV + (j >> 7), u = j & 127;
                ast4(Ut32 + ((size_t)(t+8)*32 + r)*128 + u, 0u);
            }
            asm volatile("s_waitcnt vmcnt(0)" ::: "memory");
            __syncthreads();
            if (tid == 0) ast4(&uflag[t + 8], (unsigned)(l + 1));
        }

        if (l > 0) { us16* tmp = hPrev; hPrev = hNext; hNext = tmp; }

        // ---- gemm2 phase: Tt = (Wt2 @ Ushift)^T bf16, all 256 blocks ----
        {
            const us16* Awt = a.Wt2b + (size_t)l*CC*KDIM2;
            us16* TL = Yt;                               // LDS alias (needs 9 KB)
            const int xcd = bid & 7, grp = bid >> 3;
            const int mt = (xcd >> 2)*2 + (grp & 1);     // 0..3
            const int nt = (xcd & 3)*16 + (grp >> 1);    // 0..63
            const int m0b = mt*64, n0b = nt*64;
            const int m0w = m0b + (wave & 1)*32;
            const int n0w = n0b + (wave >> 1)*32;

            // dataflow wait: Ut2 row-blocks [2nt, 2nt+9] ready at layer l
            if (tid == 0) {
                #pragma unroll 1
                for (int r = 2*nt; r < 2*nt + 10; r++)
                    while (ald4(&uflag[r]) < (unsigned)(l + 1))
                        __builtin_amdgcn_s_sleep(1);
            }
            __syncthreads();

            const us16* ap = Awt + (size_t)(m0w + l16)*KDIM2 + quad*8;
            f32x4 acc00 = {}, acc01 = {}, acc10 = {}, acc11 = {};
            bf16x8 aA0,aA1,bA0,bA1, aB0,aB1,bB0,bB1, aC0,aC1,bC0,bC1, aD0,aD1,bD0,bD1;

#define GLD(S, it) { \
    int k0 = (it)*32; \
    a##S##0 = ld8(ap + k0); \
    a##S##1 = ld8(ap + k0 + 16*KDIM2); \
    int g = k0 >> 8; \
    const us16* bp = a.Ut2 + (size_t)(n0w + (8-g)*32 + l16)*CC + (k0 & 255) + quad*8; \
    b##S##0 = ald16v(bp); \
    b##S##1 = ald16v(bp + 16*CC); }
#define GMF(S) { \
    acc00 = __builtin_amdgcn_mfma_f32_16x16x32_bf16(a##S##0, b##S##0, acc00,0,0,0); \
    acc01 = __builtin_amdgcn_mfma_f32_16x16x32_bf16(a##S##0, b##S##1, acc01,0,0,0); \
    acc10 = __builtin_amdgcn_mfma_f32_16x16x32_bf16(a##S##1, b##S##0, acc10,0,0,0); \
    acc11 = __builtin_amdgcn_mfma_f32_16x16x32_bf16(a##S##1, b##S##1, acc11,0,0,0); }

            GLD(A, 0); GLD(B, 1); GLD(C, 2); GLD(D, 3);
            #pragma unroll 1
            for (int it = 4; it <= KDIM2/32 - 4; it += 4) {
                GMF(A); GLD(A, it);
                GMF(B); GLD(B, it+1);
                GMF(C); GLD(C, it+2);
                GMF(D); GLD(D, it+3);
            }
            GMF(A); GMF(B); GMF(C); GMF(D);
#undef GLD
#undef GMF

            // epilogue: bf16 transpose via LDS, write-through store to Tt[n][c]
            #pragma unroll
            for (int r = 0; r < 4; r++) {
                int mlo = (wave & 1)*32 + quad*4 + r;
                int nlo = (wave >> 1)*32 + l16;
                TL[nlo*72 + mlo]           = f2bf(acc00[r]);
                TL[(nlo+16)*72 + mlo]      = f2bf(acc01[r]);
                TL[nlo*72 + mlo + 16]      = f2bf(acc10[r]);
                TL[(nlo+16)*72 + mlo + 16] = f2bf(acc11[r]);
            }
            __syncthreads();
            #pragma unroll
            for (int u = 0; u < 2; u++) {
                int q2 = tid + u*256;
                int row = q2 >> 3, ch = q2 & 7;
                union { ull q[2]; bf16x8 v; } tu;
                tu.v = *(const bf16x8*)(TL + row*72 + ch*8);
                us16* dp = a.Tt + (size_t)(n0b + row)*CC + m0b + ch*8;
                ast8(dp, tu.q[0]); ast8(dp + 4, tu.q[1]);
            }
        }
        gbar(a.bar);
    }

    // ---- fin phase: LN2 + residual + ReLU + pool + classifier ----
    if (t < TT) {
        unsigned* stgT = (unsigned*)Yt;
        unsigned* stgR = stgT + 3200;
        const unsigned* Hp32 = (const unsigned*)hPrev;
        for (int j = tid; j < 3200; j += 256) {
            int v = j >> 7, u = j & 127;
            stgT[j] = ald4(Tt32 + ((size_t)t*32 + v)*128 + u);
        }
        if (t >= 4)
            for (int j = tid; j < 3200; j += 256) {
                int v = j >> 7, u = j & 127;
                stgR[j] = ald4(Hp32 + ((size_t)(t-4)*32 + v)*128 + u);
            }
        __syncthreads();
        const float* btv = a.bt   + (size_t)(LL-1)*CC;
        const float* lnw = a.ln2w + (size_t)(LL-1)*CC*VV;
        const float* lnb = a.ln2b + (size_t)(LL-1)*CC*VV;
        float* sp = (float*)sH;                          // LDS alias (1 KB)
        int c = tid;
        float btc = btv[c];
        float vals[VV];
        float s = 0.f, q = 0.f;
        #pragma unroll
        for (int v = 0; v < VV; v++) {
            float xv = bf2f(((const us16*)stgT)[v*256 + c]) + btc;
            vals[v] = xv; s += xv; q += xv*xv;
        }
        blk_reduce2(s, q, red);
        float m = s * (1.f/6400.f);
        float var = q * (1.f/6400.f) - m*m;
        float rs = rsqrtf(var + 1e-5f);
        float pl = 0.f;
        #pragma unroll
        for (int v = 0; v < VV; v++) {
            float res = (t >= 4) ? bf2f(((const us16*)stgR)[v*256 + c]) : 0.f;
            float o = fmaxf((vals[v]-m)*rs*lnw[c*VV+v] + lnb[c*VV+v] + res, 0.f);
            pl += o;
        }
        sp[c] = pl * (1.f/VV);
        __syncthreads();
        if (tid < NCC) {
            float acc = a.bout[tid];
            for (int cc = 0; cc < CC; cc++) acc = fmaf(a.Wout[tid*CC+cc], sp[cc], acc);
            a.out[t*NCC + tid] = acc;
        }
    }
}

// ---------------- launch ----------------

extern "C" void kernel_launch(void* const* d_in, const int* in_sizes, int n_in,
                              void* d_out, int out_size, void* d_ws, size_t ws_size,
                              hipStream_t stream) {
    const float* x    = (const float*)d_in[0];
    const float* A    = (const float*)d_in[1];
    const float* lniw = (const float*)d_in[2];
    const float* lnib = (const float*)d_in[3];
    const float* Win  = (const float*)d_in[4];
    const float* bin  = (const float*)d_in[5];
    const float* Wg   = (const float*)d_in[6];
    const float* bg   = (const float*)d_in[7];
    const float* ln1w = (const float*)d_in[8];
    const float* ln1b = (const float*)d_in[9];
    const float* Wt   = (const float*)d_in[10];
    const float* bt   = (const float*)d_in[11];
    const float* ln2w = (const float*)d_in[12];
    const float* ln2b = (const float*)d_in[13];
    const float* imp  = (const float*)d_in[14];
    const float* Wout = (const float*)d_in[15];
    const float* bout = (const float*)d_in[16];
    float* out = (float*)d_out;

    float* ws = (float*)d_ws;
    size_t off = 0;
    auto alloc = [&](size_t n) { float* p = ws + off; off += (n + 255) & ~(size_t)255; return p; };
    float* bgAl = alloc((size_t)LL*CC*32);
    us16* HTb0 = (us16*)alloc((size_t)TT*32*CC/2);
    us16* HTb1 = (us16*)alloc((size_t)TT*32*CC/2);
    us16* Tt   = (us16*)alloc((size_t)N4*CC/2);
    us16* Wgb  = (us16*)alloc((size_t)LL*KK*CC*CC/2);
    us16* Wt2b = (us16*)alloc((size_t)LL*CC*KDIM2/2);
    us16* Ut2  = (us16*)alloc((size_t)UR*CC/2);
    us16* AlTb = (us16*)alloc((size_t)LL*KK*32*32/2);
    unsigned* bar = (unsigned*)alloc(256);     // bar[0..7] + uflag[136]
    (void)ws_size; (void)in_sizes; (void)n_in; (void)out_size;

    k_prep<<<(PTOT + 255)/256, 256, 0, stream>>>(Wg, Wt, A, imp, bg,
                                                 Wgb, Wt2b, AlTb, bgAl, bar);

    FA fa;
    fa.x = x; fa.lniw = lniw; fa.lnib = lnib; fa.Win = Win; fa.bin = bin;
    fa.bt = bt; fa.ln2w = ln2w; fa.ln2b = ln2b;
    fa.ln1w = ln1w; fa.ln1b = ln1b;
    fa.Wgb = Wgb; fa.AlTb = AlTb; fa.Wt2b = Wt2b;
    fa.bgAl = bgAl;
    fa.Wout = Wout; fa.bout = bout;
    fa.HTb0 = HTb0; fa.HTb1 = HTb1; fa.Tt = Tt; fa.Ut2 = Ut2;
    fa.bar = bar;
    fa.out = out;

    k_fused<<<dim3(GRID), dim3(256), 0, stream>>>(fa);
}

// Round 8
// 783.668 us; speedup vs baseline: 1.2847x; 1.2847x over previous
//
#include <hip/hip_runtime.h>

#define TT  128
#define CC  256
#define VV  25
#define KK  3
#define GG  9
#define LL  9
#define NCC 60
#define CINN 3
#define TV    (TT*VV)          // 3200 (input x layout)
#define KDIM2 (CC*GG)          // 2304
#define UR    ((TT+8)*32)      // 4352 Ut2 rows: row = (t+8)*32+v
#define YSTR  104              // LDS Yt row stride (shorts)
#define HSTR  264              // LDS sH row stride (shorts), bank-skewed
#define BSTR  260              // LDS B-stage row stride (shorts), bank-skewed

typedef __attribute__((ext_vector_type(8))) short bf16x8;
typedef __attribute__((ext_vector_type(4))) float f32x4;
typedef unsigned short us16;

__device__ __forceinline__ us16 f2bf(float f) {
    union { float f; unsigned u; } a; a.f = f;
    unsigned r = a.u + 0x7fff + ((a.u >> 16) & 1);
    return (us16)(r >> 16);
}
__device__ __forceinline__ float bf2f(us16 u) {
    union { unsigned u; float f; } a; a.u = ((unsigned)u) << 16; return a.f;
}
__device__ __forceinline__ bf16x8 ld8(const us16* p) { return *(const bf16x8*)p; }

// ---------------- block reduce (sum, sumsq), NW waves ----------------

template<int NW>
__device__ __forceinline__ void blk_reduce2t(float& s, float& q, float* red) {
    #pragma unroll
    for (int off = 32; off; off >>= 1) {
        s += __shfl_down(s, off);
        q += __shfl_down(q, off);
    }
    int lane = threadIdx.x & 63, w = threadIdx.x >> 6;
    if (lane == 0) { red[w] = s; red[NW + w] = q; }
    __syncthreads();
    s = 0.f; q = 0.f;
    #pragma unroll
    for (int i = 0; i < NW; i++) { s += red[i]; q += red[NW + i]; }
}

// ---------------- merged prep kernel ----------------

#define PN1 (LL*KK*CC*CC)
#define PN2 (LL*CC*CC*GG)
#define PN3 (LL*KK*32*32)
#define PN4 (LL*CC*32)
#define PTOT (PN1+PN2+PN3+PN4)

__global__ void k_prep(const float* __restrict__ Wg, const float* __restrict__ Wt,
                       const float* __restrict__ A, const float* __restrict__ imp,
                       const float* __restrict__ bg,
                       us16* __restrict__ Wgb, us16* __restrict__ Wt2b,
                       us16* __restrict__ AlTb, float* __restrict__ bgAl) {
    int i = blockIdx.x * 256 + threadIdx.x;
    if (i < PN1) {
        Wgb[i] = f2bf(Wg[i]);
    } else if (i < PN1 + PN2) {
        int j = i - PN1;
        int kk = j % (CC*GG);
        int o  = (j / (CC*GG)) % CC;
        int l  = j / (CC*CC*GG);
        int g = kk >> 8, c = kk & 255;
        Wt2b[j] = f2bf(Wt[((size_t)(l*CC + o)*CC + c)*GG + g]);
    } else if (i < PN1 + PN2 + PN3) {
        int j = i - PN1 - PN2;
        int v = j & 31, w = (j >> 5) & 31;
        int lk = j >> 10, k = lk % KK, l = lk / KK;
        float val = 0.f;
        if (v < VV && w < VV)
            val = A[(k*VV+v)*VV + w] * imp[((size_t)(l*KK+k)*VV+v)*VV + w];
        AlTb[j] = f2bf(val);
    } else if (i < PTOT) {
        int j = i - PN1 - PN2 - PN3;
        int w = j & 31, c = (j >> 5) & 255, l = j >> 13;
        float s = 0.f;
        if (w < VV) {
            for (int k = 0; k < KK; k++) {
                float col = 0.f;
                for (int v = 0; v < VV; v++)
                    col += A[(k*VV+v)*VV + w] * imp[((size_t)(l*KK+k)*VV+v)*VV + w];
                s += bg[l*KK*CC + k*CC + c] * col;
            }
        }
        bgAl[j] = s;
    }
}

// ---------------- layer-0 gcn (round-0 verified FIRST path) ----------------

__global__ __launch_bounds__(256, 1) void k_gcn0(
    const float* __restrict__ x, const float* __restrict__ lniw,
    const float* __restrict__ lnib, const float* __restrict__ Win,
    const float* __restrict__ bin,
    const us16* __restrict__ Wgb0,
    const us16* __restrict__ AlTb0, const float* __restrict__ bgAl0,
    const float* __restrict__ lnw, const float* __restrict__ lnb,
    us16* __restrict__ HTb, us16* __restrict__ Ut2) {

    const int t = blockIdx.x, tid = threadIdx.x;
    if (t >= TT) {                     // 8 history pad frames: relu(ln1_b)
        int tp = t - TT, c = tid;
        #pragma unroll
        for (int w = 0; w < 32; w++) {
            float u = (w < VV) ? fmaxf(lnb[c*VV + w], 0.f) : 0.f;
            Ut2[(size_t)(tp*32 + w)*CC + c] = f2bf(u);
        }
        return;
    }
    __shared__ __align__(16) us16 Yt[CC*YSTR];
    __shared__ __align__(16) us16 sH[32*HSTR];
    __shared__ float red[8];
    __shared__ float sx[80];
    __shared__ float sh[80];
    const int wave = tid >> 6, lane = tid & 63, quad = lane >> 4, l16 = lane & 15;

    // ---- h^0 = W_in @ LN_in(x_t) + b_in ----
    if (tid < CINN*VV)
        sx[tid] = x[(size_t)(tid/VV)*TV + t*VV + (tid%VV)];
    __syncthreads();
    {
        float s = 0.f, q = 0.f;
        for (int i = 0; i < CINN*VV; i++) { float v = sx[i]; s += v; q += v*v; }
        float m  = s * (1.f/75.f);
        float var = q * (1.f/75.f) - m*m;
        float rs = rsqrtf(var + 1e-5f);
        if (tid < CINN*VV)
            sh[tid] = (sx[tid]-m)*rs*lniw[tid] + lnib[tid];
    }
    __syncthreads();
    {
        int c = tid;
        float w0 = Win[c*3+0], w1 = Win[c*3+1], w2 = Win[c*3+2], bb = bin[c];
        #pragma unroll
        for (int v = 0; v < VV; v++) {
            float acc = bb + w0*sh[v] + w1*sh[VV+v] + w2*sh[2*VV+v];
            us16 b = f2bf(acc);
            HTb[(size_t)(t*32 + v)*CC + c] = b;
            sH[v*HSTR + c] = b;
        }
        #pragma unroll
        for (int v = VV; v < 32; v++)
            sH[v*HSTR + c] = 0;
    }
    __syncthreads();

    bf16x8 al[2][3];
    #pragma unroll
    for (int nt = 0; nt < 2; nt++)
        #pragma unroll
        for (int s = 0; s < 3; s++)
            al[nt][s] = ld8(AlTb0 + (size_t)(s*32 + nt*16 + l16)*32 + quad*8);

    bf16x8 bf[2][8];
    #pragma unroll
    for (int nt = 0; nt < 2; nt++)
        #pragma unroll
        for (int s = 0; s < 8; s++)
            bf[nt][s] = *(const bf16x8*)(sH + (nt*16 + l16)*HSTR + s*32 + quad*8);

    bf16x8 wA0,wA1,wA2,wA3,wA4,wA5,wA6,wA7;
    bf16x8 wB0,wB1,wB2,wB3,wB4,wB5,wB6,wB7;
    bf16x8 wC0,wC1,wC2,wC3,wC4,wC5,wC6,wC7;

#define PLD(S, mtv) { \
    const us16* ap_ = Wgb0 + (size_t)(wave*192 + (mtv)*16 + l16)*CC + quad*8; \
    S##0 = ld8(ap_);       S##1 = ld8(ap_ + 32); \
    S##2 = ld8(ap_ + 64);  S##3 = ld8(ap_ + 96); \
    S##4 = ld8(ap_ + 128); S##5 = ld8(ap_ + 160); \
    S##6 = ld8(ap_ + 192); S##7 = ld8(ap_ + 224); }
#define PMFW(S, mtv) { \
    f32x4 p0a = {}, p0b = {}, p1a = {}, p1b = {}; \
    p0a = __builtin_amdgcn_mfma_f32_16x16x32_bf16(S##0, bf[0][0], p0a,0,0,0); \
    p1a = __builtin_amdgcn_mfma_f32_16x16x32_bf16(S##0, bf[1][0], p1a,0,0,0); \
    p0b = __builtin_amdgcn_mfma_f32_16x16x32_bf16(S##1, bf[0][1], p0b,0,0,0); \
    p1b = __builtin_amdgcn_mfma_f32_16x16x32_bf16(S##1, bf[1][1], p1b,0,0,0); \
    p0a = __builtin_amdgcn_mfma_f32_16x16x32_bf16(S##2, bf[0][2], p0a,0,0,0); \
    p1a = __builtin_amdgcn_mfma_f32_16x16x32_bf16(S##2, bf[1][2], p1a,0,0,0); \
    p0b = __builtin_amdgcn_mfma_f32_16x16x32_bf16(S##3, bf[0][3], p0b,0,0,0); \
    p1b = __builtin_amdgcn_mfma_f32_16x16x32_bf16(S##3, bf[1][3], p1b,0,0,0); \
    p0a = __builtin_amdgcn_mfma_f32_16x16x32_bf16(S##4, bf[0][4], p0a,0,0,0); \
    p1a = __builtin_amdgcn_mfma_f32_16x16x32_bf16(S##4, bf[1][4], p1a,0,0,0); \
    p0b = __builtin_amdgcn_mfma_f32_16x16x32_bf16(S##5, bf[0][5], p0b,0,0,0); \
    p1b = __builtin_amdgcn_mfma_f32_16x16x32_bf16(S##5, bf[1][5], p1b,0,0,0); \
    p0a = __builtin_amdgcn_mfma_f32_16x16x32_bf16(S##6, bf[0][6], p0a,0,0,0); \
    p1a = __builtin_amdgcn_mfma_f32_16x16x32_bf16(S##6, bf[1][6], p1a,0,0,0); \
    p0b = __builtin_amdgcn_mfma_f32_16x16x32_bf16(S##7, bf[0][7], p0b,0,0,0); \
    p1b = __builtin_amdgcn_mfma_f32_16x16x32_bf16(S##7, bf[1][7], p1b,0,0,0); \
    int mb_ = wave*192 + (mtv)*16 + quad*4; \
    _Pragma("unroll") \
    for (int r_ = 0; r_ < 4; r_++) { \
        int m_ = mb_ + r_; \
        int base_ = (m_ & 255)*YSTR + (m_ >> 8)*32 + l16; \
        Yt[base_]      = f2bf(p0a[r_] + p0b[r_]); \
        Yt[base_ + 16] = f2bf(p1a[r_] + p1b[r_]); \
    } }

    PLD(wA, 0); PLD(wB, 1); PLD(wC, 2);
    #pragma unroll 1
    for (int mt = 0; mt < 9; mt += 3) {
        PMFW(wA, mt);     PLD(wA, mt + 3);
        PMFW(wB, mt + 1); PLD(wB, mt + 4);
        PMFW(wC, mt + 2); PLD(wC, mt + 5);
    }
    PMFW(wA, 9); PMFW(wB, 10); PMFW(wC, 11);
#undef PLD
#undef PMFW
    __syncthreads();

    f32x4 z[4][2];
    #pragma unroll
    for (int mt = 0; mt < 4; mt++) { z[mt][0] = (f32x4){}; z[mt][1] = (f32x4){}; }
    #pragma unroll
    for (int mt = 0; mt < 4; mt++)
        #pragma unroll
        for (int s = 0; s < 3; s++) {
            bf16x8 av = *(const bf16x8*)(Yt + (wave*64 + mt*16 + l16)*YSTR + s*32 + quad*8);
            z[mt][0] = __builtin_amdgcn_mfma_f32_16x16x32_bf16(av, al[0][s], z[mt][0], 0,0,0);
            z[mt][1] = __builtin_amdgcn_mfma_f32_16x16x32_bf16(av, al[1][s], z[mt][1], 0,0,0);
        }

    float s_ = 0.f, q_ = 0.f;
    #pragma unroll
    for (int mt = 0; mt < 4; mt++)
        #pragma unroll
        for (int nt = 0; nt < 2; nt++)
            #pragma unroll
            for (int r = 0; r < 4; r++) {
                int c = wave*64 + mt*16 + quad*4 + r;
                int w = nt*16 + l16;
                float zb = z[mt][nt][r] + bgAl0[c*32 + w];
                z[mt][nt][r] = zb;
                if (w < VV) { s_ += zb; q_ += zb*zb; }
            }
    blk_reduce2t<4>(s_, q_, red);
    float m = s_ * (1.f/6400.f);
    float var = q_ * (1.f/6400.f) - m*m;
    float rs = rsqrtf(var + 1e-5f);
    #pragma unroll
    for (int mt = 0; mt < 4; mt++)
        #pragma unroll
        for (int nt = 0; nt < 2; nt++) {
            int w = nt*16 + l16;
            if (w < VV) {
                int c0 = wave*64 + mt*16 + quad*4;
                ushort4 pk;
                float u0 = fmaxf((z[mt][nt][0]-m)*rs*lnw[(c0+0)*VV+w] + lnb[(c0+0)*VV+w], 0.f);
                float u1 = fmaxf((z[mt][nt][1]-m)*rs*lnw[(c0+1)*VV+w] + lnb[(c0+1)*VV+w], 0.f);
                float u2 = fmaxf((z[mt][nt][2]-m)*rs*lnw[(c0+2)*VV+w] + lnb[(c0+2)*VV+w], 0.f);
                float u3 = fmaxf((z[mt][nt][3]-m)*rs*lnw[(c0+3)*VV+w] + lnb[(c0+3)*VV+w], 0.f);
                pk.x = f2bf(u0); pk.y = f2bf(u1); pk.z = f2bf(u2); pk.w = f2bf(u3);
                *(ushort4*)(Ut2 + (size_t)((t+8)*32 + w)*CC + c0) = pk;
            }
        }
    #pragma unroll
    for (int r = VV; r < 32; r++)
        Ut2[(size_t)((t+8)*32 + r)*CC + tid] = 0;
}

// ---------------- merged layer kernel ----------------
// Block t (512 threads, 8 waves): computes T(l-1)[c][t*32+v] = Wt2[l-1] (*) U(l-1)
// in registers (M=256 over 8 waves, N=32 = frame, K=2304; B staged per-g in LDS
// -- FULL 256 channels per row: 512 threads x 16 shorts -- A streamed from L2),
// then (FIN=0) h^l -> graph-conv -> U(l); (FIN=1) final pool+classifier.

template<int FIN>
__global__ __launch_bounds__(512, 1) void k_layer(
    const us16* __restrict__ Awt,                        // Wt2b slice, layer l-1
    const float* __restrict__ btv, const float* __restrict__ l2w,
    const float* __restrict__ l2b,
    const us16* __restrict__ HTprev, const us16* __restrict__ Uin,
    const us16* __restrict__ WgbL, const us16* __restrict__ AlTbL,
    const float* __restrict__ bgAlL,
    const float* __restrict__ lnwL, const float* __restrict__ lnbL,
    us16* __restrict__ HTout, us16* __restrict__ Uout,
    const float* __restrict__ Wout, const float* __restrict__ bout,
    float* __restrict__ out) {

    const int t = blockIdx.x, tid = threadIdx.x;
    __shared__ __align__(16) us16 Yt[CC*YSTR];           // 53.2 KB (aliases Bst)
    __shared__ __align__(16) us16 sH[32*HSTR];           // 16.9 KB (T tile, then h)
    __shared__ float red[16];
    const int wave = tid >> 6, lane = tid & 63, quad = lane >> 4, l16 = lane & 15;

    if (FIN == 0 && t >= TT) {                           // pad frames: relu(ln1_b)
        if (tid < CC) {
            int tp = t - TT, c = tid;
            #pragma unroll
            for (int w = 0; w < 32; w++) {
                float u = (w < VV) ? fmaxf(lnbL[c*VV + w], 0.f) : 0.f;
                Uout[(size_t)(tp*32 + w)*CC + c] = f2bf(u);
            }
        }
        return;
    }

    // ---- gemm2 for frame t: T[c][v], c = wave*32 + frag, v = 0..31 ----
    us16* Bst = Yt;                                      // [2][32][BSTR]
    const us16* ap = Awt + (size_t)(wave*32 + l16)*KDIM2 + quad*8;
    f32x4 acc00 = {}, acc01 = {}, acc10 = {}, acc11 = {};
    const int brow = tid >> 4, bcol = (tid & 15) * 16;   // 512 thr x 16 shorts = 32x256
    const us16* ubase = Uin + (size_t)((t+8)*32 + brow)*CC + bcol;   // g=0 window
    {
        bf16x8 b0 = ld8(ubase), b1 = ld8(ubase + 8);
        *(bf16x8*)(Bst + brow*BSTR + bcol)     = b0;
        *(bf16x8*)(Bst + brow*BSTR + bcol + 8) = b1;
    }
    __syncthreads();
    #pragma unroll 1
    for (int g = 0; g < 9; g++) {
        const us16* apg = ap + g*256;
        bf16x8 aL[8], aH[8];
        #pragma unroll
        for (int s = 0; s < 8; s++) {
            aL[s] = ld8(apg + s*32);
            aH[s] = ld8(apg + 16*KDIM2 + s*32);
        }
        bf16x8 bn0 = {}, bn1 = {};
        if (g < 8) {
            const us16* un = ubase - (size_t)(g+1)*32*CC;
            bn0 = ld8(un); bn1 = ld8(un + 8);
        }
        const us16* bb = Bst + (g & 1)*(32*BSTR);
        #pragma unroll
        for (int s = 0; s < 8; s++) {
            bf16x8 b0 = *(const bf16x8*)(bb + l16*BSTR + s*32 + quad*8);
            bf16x8 b1 = *(const bf16x8*)(bb + (l16+16)*BSTR + s*32 + quad*8);
            acc00 = __builtin_amdgcn_mfma_f32_16x16x32_bf16(aL[s], b0, acc00,0,0,0);
            acc01 = __builtin_amdgcn_mfma_f32_16x16x32_bf16(aL[s], b1, acc01,0,0,0);
            acc10 = __builtin_amdgcn_mfma_f32_16x16x32_bf16(aH[s], b0, acc10,0,0,0);
            acc11 = __builtin_amdgcn_mfma_f32_16x16x32_bf16(aH[s], b1, acc11,0,0,0);
        }
        __syncthreads();
        if (g < 8) {
            us16* bw = Bst + ((g+1) & 1)*(32*BSTR) + brow*BSTR + bcol;
            *(bf16x8*)bw       = bn0;
            *(bf16x8*)(bw + 8) = bn1;
        }
        __syncthreads();
    }

    // ---- acc frags -> sH[v][c] (bf16 T tile) ----
    #pragma unroll
    for (int mh = 0; mh < 2; mh++)
        #pragma unroll
        for (int nh = 0; nh < 2; nh++) {
            f32x4 av = (mh == 0) ? (nh == 0 ? acc00 : acc01)
                                 : (nh == 0 ? acc10 : acc11);
            int v = l16 + nh*16;
            int cb = wave*32 + quad*4 + mh*16;
            #pragma unroll
            for (int r = 0; r < 4; r += 2) {
                ushort2 p;
                p.x = f2bf(av[r]); p.y = f2bf(av[r+1]);
                *(ushort2*)(sH + v*HSTR + cb + r) = p;
            }
        }
    __syncthreads();

    // ---- LN2 prologue (threads 0..255 own one channel each) ----
    float vals[VV];
    float s_ = 0.f, q_ = 0.f;
    if (tid < CC) {
        float btc = btv[tid];
        #pragma unroll
        for (int v = 0; v < VV; v++) {
            float xv = bf2f(sH[v*HSTR + tid]) + btc;
            vals[v] = xv; s_ += xv; q_ += xv*xv;
        }
    }
    blk_reduce2t<8>(s_, q_, red);
    float m = s_ * (1.f/6400.f);
    float var = q_ * (1.f/6400.f) - m*m;
    float rs = rsqrtf(var + 1e-5f);

    if (FIN == 1) {
        // ---- fin: relu(LN2+resid) -> pool -> classifier ----
        float* sp = (float*)Yt;
        if (tid < CC) {
            int c = tid;
            float pl = 0.f;
            #pragma unroll
            for (int v = 0; v < VV; v++) {
                float res = (t >= 4) ? bf2f(HTprev[(size_t)((t-4)*32 + v)*CC + c]) : 0.f;
                float o = fmaxf((vals[v]-m)*rs*l2w[c*VV+v] + l2b[c*VV+v] + res, 0.f);
                pl += o;
            }
            sp[c] = pl * (1.f/VV);
        }
        __syncthreads();
        if (tid < NCC) {
            float acc = bout[tid];
            for (int cc = 0; cc < CC; cc++) acc = fmaf(Wout[tid*CC+cc], sp[cc], acc);
            out[t*NCC + tid] = acc;
        }
        return;
    }

    // ---- h^l = relu(LN2(T+bt) + resid) -> sH + HTout ----
    if (tid < CC) {
        int c = tid;
        #pragma unroll
        for (int v = 0; v < VV; v++) {
            float res = (t >= 4) ? bf2f(HTprev[(size_t)((t-4)*32 + v)*CC + c]) : 0.f;
            float o = fmaxf((vals[v]-m)*rs*l2w[c*VV+v] + l2b[c*VV+v] + res, 0.f);
            us16 b = f2bf(o);
            HTout[(size_t)(t*32 + v)*CC + c] = b;
            sH[v*HSTR + c] = b;
        }
        #pragma unroll
        for (int v = VV; v < 32; v++)
            sH[v*HSTR + c] = 0;
    }
    __syncthreads();

    // ---- graph conv: phase 1 (Y = Wg @ h), 8 waves x 6 m-tiles ----
    bf16x8 al[2][3];
    #pragma unroll
    for (int nt = 0; nt < 2; nt++)
        #pragma unroll
        for (int s = 0; s < 3; s++)
            al[nt][s] = ld8(AlTbL + (size_t)(s*32 + nt*16 + l16)*32 + quad*8);

    bf16x8 bf[2][8];
    #pragma unroll
    for (int nt = 0; nt < 2; nt++)
        #pragma unroll
        for (int s = 0; s < 8; s++)
            bf[nt][s] = *(const bf16x8*)(sH + (nt*16 + l16)*HSTR + s*32 + quad*8);

    bf16x8 wA0,wA1,wA2,wA3,wA4,wA5,wA6,wA7;
    bf16x8 wB0,wB1,wB2,wB3,wB4,wB5,wB6,wB7;
    bf16x8 wC0,wC1,wC2,wC3,wC4,wC5,wC6,wC7;

#define PLD(S, mtv) { \
    const us16* ap_ = WgbL + (size_t)(wave*96 + (mtv)*16 + l16)*CC + quad*8; \
    S##0 = ld8(ap_);       S##1 = ld8(ap_ + 32); \
    S##2 = ld8(ap_ + 64);  S##3 = ld8(ap_ + 96); \
    S##4 = ld8(ap_ + 128); S##5 = ld8(ap_ + 160); \
    S##6 = ld8(ap_ + 192); S##7 = ld8(ap_ + 224); }
#define PMFW(S, mtv) { \
    f32x4 p0a = {}, p0b = {}, p1a = {}, p1b = {}; \
    p0a = __builtin_amdgcn_mfma_f32_16x16x32_bf16(S##0, bf[0][0], p0a,0,0,0); \
    p1a = __builtin_amdgcn_mfma_f32_16x16x32_bf16(S##0, bf[1][0], p1a,0,0,0); \
    p0b = __builtin_amdgcn_mfma_f32_16x16x32_bf16(S##1, bf[0][1], p0b,0,0,0); \
    p1b = __builtin_amdgcn_mfma_f32_16x16x32_bf16(S##1, bf[1][1], p1b,0,0,0); \
    p0a = __builtin_amdgcn_mfma_f32_16x16x32_bf16(S##2, bf[0][2], p0a,0,0,0); \
    p1a = __builtin_amdgcn_mfma_f32_16x16x32_bf16(S##2, bf[1][2], p1a,0,0,0); \
    p0b = __builtin_amdgcn_mfma_f32_16x16x32_bf16(S##3, bf[0][3], p0b,0,0,0); \
    p1b = __builtin_amdgcn_mfma_f32_16x16x32_bf16(S##3, bf[1][3], p1b,0,0,0); \
    p0a = __builtin_amdgcn_mfma_f32_16x16x32_bf16(S##4, bf[0][4], p0a,0,0,0); \
    p1a = __builtin_amdgcn_mfma_f32_16x16x32_bf16(S##4, bf[1][4], p1a,0,0,0); \
    p0b = __builtin_amdgcn_mfma_f32_16x16x32_bf16(S##5, bf[0][5], p0b,0,0,0); \
    p1b = __builtin_amdgcn_mfma_f32_16x16x32_bf16(S##5, bf[1][5], p1b,0,0,0); \
    p0a = __builtin_amdgcn_mfma_f32_16x16x32_bf16(S##6, bf[0][6], p0a,0,0,0); \
    p1a = __builtin_amdgcn_mfma_f32_16x16x32_bf16(S##6, bf[1][6], p1a,0,0,0); \
    p0b = __builtin_amdgcn_mfma_f32_16x16x32_bf16(S##7, bf[0][7], p0b,0,0,0); \
    p1b = __builtin_amdgcn_mfma_f32_16x16x32_bf16(S##7, bf[1][7], p1b,0,0,0); \
    int mb_ = wave*96 + (mtv)*16 + quad*4; \
    _Pragma("unroll") \
    for (int r_ = 0; r_ < 4; r_++) { \
        int m_ = mb_ + r_; \
        int base_ = (m_ & 255)*YSTR + (m_ >> 8)*32 + l16; \
        Yt[base_]      = f2bf(p0a[r_] + p0b[r_]); \
        Yt[base_ + 16] = f2bf(p1a[r_] + p1b[r_]); \
    } }

    PLD(wA, 0); PLD(wB, 1); PLD(wC, 2);
    PMFW(wA, 0); PLD(wA, 3);
    PMFW(wB, 1); PLD(wB, 4);
    PMFW(wC, 2); PLD(wC, 5);
    PMFW(wA, 3); PMFW(wB, 4); PMFW(wC, 5);
#undef PLD
#undef PMFW
    __syncthreads();

    // ---- phase 2: Z[c][w], 8 waves x 2 c-tiles ----
    f32x4 z[2][2];
    z[0][0] = (f32x4){}; z[0][1] = (f32x4){};
    z[1][0] = (f32x4){}; z[1][1] = (f32x4){};
    #pragma unroll
    for (int mt = 0; mt < 2; mt++)
        #pragma unroll
        for (int s = 0; s < 3; s++) {
            bf16x8 av = *(const bf16x8*)(Yt + (wave*32 + mt*16 + l16)*YSTR + s*32 + quad*8);
            z[mt][0] = __builtin_amdgcn_mfma_f32_16x16x32_bf16(av, al[0][s], z[mt][0], 0,0,0);
            z[mt][1] = __builtin_amdgcn_mfma_f32_16x16x32_bf16(av, al[1][s], z[mt][1], 0,0,0);
        }

    // ---- bias fold + LN1 + ReLU -> Uout ----
    float su = 0.f, qu = 0.f;
    #pragma unroll
    for (int mt = 0; mt < 2; mt++)
        #pragma unroll
        for (int nt = 0; nt < 2; nt++)
            #pragma unroll
            for (int r = 0; r < 4; r++) {
                int c = wave*32 + mt*16 + quad*4 + r;
                int w = nt*16 + l16;
                float zb = z[mt][nt][r] + bgAlL[c*32 + w];
                z[mt][nt][r] = zb;
                if (w < VV) { su += zb; qu += zb*zb; }
            }
    blk_reduce2t<8>(su, qu, red);
    float mu = su * (1.f/6400.f);
    float vu = qu * (1.f/6400.f) - mu*mu;
    float ru = rsqrtf(vu + 1e-5f);
    #pragma unroll
    for (int mt = 0; mt < 2; mt++)
        #pragma unroll
        for (int nt = 0; nt < 2; nt++) {
            int w = nt*16 + l16;
            if (w < VV) {
                int c0 = wave*32 + mt*16 + quad*4;
                ushort4 pk;
                float u0 = fmaxf((z[mt][nt][0]-mu)*ru*lnwL[(c0+0)*VV+w] + lnbL[(c0+0)*VV+w], 0.f);
                float u1 = fmaxf((z[mt][nt][1]-mu)*ru*lnwL[(c0+1)*VV+w] + lnbL[(c0+1)*VV+w], 0.f);
                float u2 = fmaxf((z[mt][nt][2]-mu)*ru*lnwL[(c0+2)*VV+w] + lnbL[(c0+2)*VV+w], 0.f);
                float u3 = fmaxf((z[mt][nt][3]-mu)*ru*lnwL[(c0+3)*VV+w] + lnbL[(c0+3)*VV+w], 0.f);
                pk.x = f2bf(u0); pk.y = f2bf(u1); pk.z = f2bf(u2); pk.w = f2bf(u3);
                *(ushort4*)(Uout + (size_t)((t+8)*32 + w)*CC + c0) = pk;
            }
        }
    if (tid < CC) {
        #pragma unroll
        for (int r = VV; r < 32; r++)
            Uout[(size_t)((t+8)*32 + r)*CC + tid] = 0;
    }
}

// ---------------- launch ----------------

extern "C" void kernel_launch(void* const* d_in, const int* in_sizes, int n_in,
                              void* d_out, int out_size, void* d_ws, size_t ws_size,
                              hipStream_t stream) {
    const float* x    = (const float*)d_in[0];
    const float* A    = (const float*)d_in[1];
    const float* lniw = (const float*)d_in[2];
    const float* lnib = (const float*)d_in[3];
    const float* Win  = (const float*)d_in[4];
    const float* bin  = (const float*)d_in[5];
    const float* Wg   = (const float*)d_in[6];
    const float* bg   = (const float*)d_in[7];
    const float* ln1w = (const float*)d_in[8];
    const float* ln1b = (const float*)d_in[9];
    const float* Wt   = (const float*)d_in[10];
    const float* bt   = (const float*)d_in[11];
    const float* ln2w = (const float*)d_in[12];
    const float* ln2b = (const float*)d_in[13];
    const float* imp  = (const float*)d_in[14];
    const float* Wout = (const float*)d_in[15];
    const float* bout = (const float*)d_in[16];
    float* out = (float*)d_out;

    float* ws = (float*)d_ws;
    size_t off = 0;
    auto alloc = [&](size_t n) { float* p = ws + off; off += (n + 255) & ~(size_t)255; return p; };
    float* bgAl = alloc((size_t)LL*CC*32);
    us16* HTb0 = (us16*)alloc((size_t)TT*32*CC/2);
    us16* HTb1 = (us16*)alloc((size_t)TT*32*CC/2);
    us16* Wgb  = (us16*)alloc((size_t)LL*KK*CC*CC/2);
    us16* Wt2b = (us16*)alloc((size_t)LL*CC*KDIM2/2);
    us16* UA   = (us16*)alloc((size_t)UR*CC/2);
    us16* UB   = (us16*)alloc((size_t)UR*CC/2);
    us16* AlTb = (us16*)alloc((size_t)LL*KK*32*32/2);
    (void)ws_size; (void)in_sizes; (void)n_in; (void)out_size;

    k_prep<<<(PTOT + 255)/256, 256, 0, stream>>>(Wg, Wt, A, imp, bg,
                                                 Wgb, Wt2b, AlTb, bgAl);

    k_gcn0<<<TT + 8, 256, 0, stream>>>(x, lniw, lnib, Win, bin,
                                       Wgb, AlTb, bgAl, ln1w, ln1b,
                                       HTb0, UA);

    us16* Ubuf[2] = { UA, UB };
    us16* Hbuf[2] = { HTb0, HTb1 };
    for (int l = 1; l <= 8; l++) {
        k_layer<0><<<TT + 8, 512, 0, stream>>>(
            Wt2b + (size_t)(l-1)*CC*KDIM2,
            bt + (size_t)(l-1)*CC,
            ln2w + (size_t)(l-1)*CC*VV, ln2b + (size_t)(l-1)*CC*VV,
            Hbuf[(l-1) & 1], Ubuf[(l-1) & 1],
            Wgb + (size_t)l*KK*CC*CC,
            AlTb + (size_t)l*KK*32*32, bgAl + (size_t)l*CC*32,
            ln1w + (size_t)l*CC*VV, ln1b + (size_t)l*CC*VV,
            Hbuf[l & 1], Ubuf[l & 1],
            nullptr, nullptr, nullptr);
    }
    k_layer<1><<<TT, 512, 0, stream>>>(
        Wt2b + (size_t)8*CC*KDIM2,
        bt + (size_t)8*CC,
        ln2w + (size_t)8*CC*VV, ln2b + (size_t)8*CC*VV,
        Hbuf[0], Ubuf[0],
        nullptr, nullptr, nullptr, nullptr, nullptr,
        nullptr, nullptr,
        Wout, bout, out);
}